// Round 22
// baseline (474.687 us; speedup 1.0000x reference)
//
#include <hip/hip_runtime.h>

typedef _Float16 f16;
typedef __attribute__((ext_vector_type(4))) _Float16 f16x4;
typedef __attribute__((ext_vector_type(8))) _Float16 f16x8;
typedef __attribute__((ext_vector_type(4))) float    f32x4;

static constexpr int NROWS = 65536;
static constexpr int D_IN  = 768;
static constexpr int D_EMB = 128;
static constexpr long LOSS_OFF  = (long)NROWS * D_EMB;   // 8388608
static constexpr long CODES_OFF = LOSS_OFF + 1;

// weight/codebook plane arena at ws+WOFF (offsets in halves)
static constexpr long WOFF = 201326592L;
static constexpr long WE1H = 0,       WE1L = 589824;
static constexpr long WE2H = 1179648, WE2L = 1277952;
static constexpr long WD1F = 1376256, WD2F = 1392640;   // decoder f16 cast
static constexpr long E0H = 1409024, E0L = 1410048;     // codebook planes
static constexpr long E1H = 1411072, E1L = 1419264;
static constexpr long E2H = 1427456, E2L = 1492992;
static constexpr long PARTIAL_B = WOFF + 4194304L;      // 512 f32
static constexpr long NORM_B    = WOFF + 4198400L;      // 584 f32

__device__ __forceinline__ float dot4(float4 a, float4 b){
  return fmaf(a.x,b.x, fmaf(a.y,b.y, fmaf(a.z,b.z, a.w*b.w)));
}

// fp32 -> f16 hi + f16 lo*2^-11 (lo pre-scaled by 2048, stays normal-range)
__device__ __forceinline__ void split4(float4 v, f16x4& hi, f16x4& lo){
  _Float16 h0=(_Float16)v.x, h1=(_Float16)v.y, h2=(_Float16)v.z, h3=(_Float16)v.w;
  hi[0]=h0; hi[1]=h1; hi[2]=h2; hi[3]=h3;
  lo[0]=(_Float16)((v.x-(float)h0)*2048.0f);
  lo[1]=(_Float16)((v.y-(float)h1)*2048.0f);
  lo[2]=(_Float16)((v.z-(float)h2)*2048.0f);
  lo[3]=(_Float16)((v.w-(float)h3)*2048.0f);
}

__device__ __forceinline__ void split8_reg(const float* v, f16x8& hi, f16x8& lo){
#pragma unroll
  for (int i = 0; i < 8; i++){
    _Float16 h = (_Float16)v[i];
    hi[i] = h;
    lo[i] = (_Float16)((v[i]-(float)h)*2048.0f);
  }
}

// ---------------------------------------------------------------------------
// One-shot prep (validated r16): weights+codebooks -> planes.
// ---------------------------------------------------------------------------
__global__ __launch_bounds__(256)
void split_weights_kernel(const float* __restrict__ We1, const float* __restrict__ We2,
                          const float* __restrict__ Wd1, const float* __restrict__ Wd2,
                          const float* __restrict__ E0,  const float* __restrict__ E1,
                          const float* __restrict__ E2,  f16* __restrict__ wp){
  int t = blockIdx.x*256 + threadIdx.x;
  if (t >= 198912) return;
  const float* src; long o4; long hO, lO; bool dual = true;
  if      (t < 147456){ src=We1; o4=t;        hO=WE1H; lO=WE1L; }
  else if (t < 172032){ src=We2; o4=t-147456; hO=WE2H; lO=WE2L; }
  else if (t < 176128){ src=Wd1; o4=t-172032; hO=WD1F; lO=0; dual=false; }
  else if (t < 180224){ src=Wd2; o4=t-176128; hO=WD2F; lO=0; dual=false; }
  else if (t < 180480){ src=E0;  o4=t-180224; hO=E0H;  lO=E0L; }
  else if (t < 182528){ src=E1;  o4=t-180480; hO=E1H;  lO=E1L; }
  else                { src=E2;  o4=t-182528; hO=E2H;  lO=E2L; }
  float4 v = *(const float4*)(src + o4*4);
  if (dual){
    f16x4 h4, l4; split4(v, h4, l4);
    *(f16x4*)(wp + hO + o4*4) = h4;
    *(f16x4*)(wp + lO + o4*4) = l4;
  } else {
    f16x4 h4; h4[0]=(_Float16)v.x; h4[1]=(_Float16)v.y; h4[2]=(_Float16)v.z; h4[3]=(_Float16)v.w;
    *(f16x4*)(wp + hO + o4*4) = h4;
  }
}

// Codebook norms, exact quarter-dot summation order (validated r16).
__global__ __launch_bounds__(256)
void enorm_kernel(const float* __restrict__ E0, const float* __restrict__ E1,
                  const float* __restrict__ E2, float* __restrict__ norms){
  int t = blockIdx.x*256 + threadIdx.x;
  if (t >= 584) return;
  const float* row;
  if (t < 8)       row = E0 + (long)t*128;
  else if (t < 72) row = E1 + (long)(t-8)*128;
  else             row = E2 + (long)(t-72)*128;
  float q[4];
#pragma unroll
  for (int sq = 0; sq < 4; sq++){
    float s = 0.f;
#pragma unroll
    for (int j = 0; j < 8; j++){
      float4 v = *(const float4*)(row + sq*32 + j*4);
      s += dot4(v, v);
    }
    q[sq] = s;
  }
  norms[t] = ((q[0] + q[1]) + q[2]) + q[3];
}

// ---------------------------------------------------------------------------
// Encoder GEMM1 (r17/r21 validated best): BM=256, BN=128, BK=32, 512 threads,
// double-buffered LDS, ONE barrier per K-step, bijective XCD swizzle.
// ---------------------------------------------------------------------------
template<bool RELU>
__global__ __launch_bounds__(512, 2)
void gemm_v2_kernel(const float* __restrict__ A,
                    const f16* __restrict__ Bhg, const f16* __restrict__ Blg,
                    const float* __restrict__ bias, float* __restrict__ C,
                    int M, int N, int K){
  constexpr int RS = 40;
  __shared__ f16 AhL[2][256*RS];
  __shared__ f16 AlL[2][256*RS];
  __shared__ f16 BhL[2][128*RS];
  __shared__ f16 BlL[2][128*RS];

  const int tid = threadIdx.x;
  const int wave = tid >> 6, lane = tid & 63;
  const int wm = wave >> 1, wn = wave & 1;
  const int lr = lane & 15, lg = lane >> 4;

  const int gx  = gridDim.x;
  const int lid = blockIdx.y * gx + blockIdx.x;
  const int xcd = lid & 7;
  const int rr  = lid >> 3;
  const int bx  = rr % gx;
  const int by  = (rr / gx) * 8 + xcd;

  const long m0 = (long)by * 256;
  const long n0 = (long)bx * 128;

  const int ar = tid >> 3;
  const int ac = tid & 7;
  const int br = tid >> 2;
  const int bkc = tid & 3;

  const int nt = K >> 5;

  float4 pa[4];
  f16x8 pbh, pbl;

#pragma unroll
  for (int i = 0; i < 4; i++)
    pa[i] = *(const float4*)(A + (m0 + i*64 + ar)*K + ac*4);
  pbh = *(const f16x8*)(Bhg + (n0 + br)*K + bkc*8);
  pbl = *(const f16x8*)(Blg + (n0 + br)*K + bkc*8);

#pragma unroll
  for (int i = 0; i < 4; i++){
    f16x4 h4, l4; split4(pa[i], h4, l4);
    *(f16x4*)&AhL[0][(i*64 + ar)*RS + ac*4] = h4;
    *(f16x4*)&AlL[0][(i*64 + ar)*RS + ac*4] = l4;
  }
  *(f16x8*)&BhL[0][br*RS + bkc*8] = pbh;
  *(f16x8*)&BlL[0][br*RS + bkc*8] = pbl;
  __syncthreads();

  f32x4 accm[4][4], accc[4][4];
#pragma unroll
  for (int i = 0; i < 4; i++)
#pragma unroll
    for (int j = 0; j < 4; j++){
      accm[i][j] = (f32x4){0.f,0.f,0.f,0.f};
      accc[i][j] = (f32x4){0.f,0.f,0.f,0.f};
    }

  int cur = 0;
  for (int t = 0; t < nt; t++){
    const bool more = (t + 1 < nt);
    if (more){
      const long ko = (long)(t+1) * 32;
#pragma unroll
      for (int i = 0; i < 4; i++)
        pa[i] = *(const float4*)(A + (m0 + i*64 + ar)*K + ko + ac*4);
      pbh = *(const f16x8*)(Bhg + (n0 + br)*K + ko + bkc*8);
      pbl = *(const f16x8*)(Blg + (n0 + br)*K + ko + bkc*8);
    }

    f16x8 ah[4], al[4];
#pragma unroll
    for (int mi = 0; mi < 4; mi++){
      int row = wm*64 + mi*16 + lr;
      ah[mi] = *(const f16x8*)&AhL[cur][row*RS + lg*8];
      al[mi] = *(const f16x8*)&AlL[cur][row*RS + lg*8];
    }
#pragma unroll
    for (int ni = 0; ni < 4; ni++){
      int col = wn*64 + ni*16 + lr;
      f16x8 bh = *(const f16x8*)&BhL[cur][col*RS + lg*8];
      f16x8 bl = *(const f16x8*)&BlL[cur][col*RS + lg*8];
#pragma unroll
      for (int mi = 0; mi < 4; mi++){
        accm[mi][ni] = __builtin_amdgcn_mfma_f32_16x16x32_f16(ah[mi], bh, accm[mi][ni], 0, 0, 0);
        accc[mi][ni] = __builtin_amdgcn_mfma_f32_16x16x32_f16(ah[mi], bl, accc[mi][ni], 0, 0, 0);
        accc[mi][ni] = __builtin_amdgcn_mfma_f32_16x16x32_f16(al[mi], bh, accc[mi][ni], 0, 0, 0);
      }
    }

    if (more){
      int nb = cur ^ 1;
#pragma unroll
      for (int i = 0; i < 4; i++){
        f16x4 h4, l4; split4(pa[i], h4, l4);
        *(f16x4*)&AhL[nb][(i*64 + ar)*RS + ac*4] = h4;
        *(f16x4*)&AlL[nb][(i*64 + ar)*RS + ac*4] = l4;
      }
      *(f16x8*)&BhL[nb][br*RS + bkc*8] = pbh;
      *(f16x8*)&BlL[nb][br*RS + bkc*8] = pbl;
      __syncthreads();
      cur = nb;
    }
  }

  float bv[4];
#pragma unroll
  for (int ni = 0; ni < 4; ni++) bv[ni] = bias[n0 + wn*64 + ni*16 + lr];
#pragma unroll
  for (int mi = 0; mi < 4; mi++){
#pragma unroll
    for (int ni = 0; ni < 4; ni++){
#pragma unroll
      for (int r = 0; r < 4; r++){
        float v = accm[mi][ni][r] + accc[mi][ni][r]*(1.0f/2048.0f) + bv[ni];
        if (RELU) v = fmaxf(v, 0.f);
        long row = m0 + wm*64 + mi*16 + lg*4 + r;
        C[row*N + n0 + wn*64 + ni*16 + lr] = v;
      }
    }
  }
}

// ---------------------------------------------------------------------------
// FUSED: GEMM2 (z tile in LDS) + residual-VQ + dec1 + dec2, per 128-row block.
// 512 blocks x 256 threads. Phases sequential in one LDS arena:
//   P1 GEMM2 128x128 dbuf (r20-validated math) -> z in acc -> rs (LDS fp32)
//   P2 VQ (r16-validated math, 2 row-groups/wave) -> codes/loss; q -> rs
//   P3 dec1/dec2 (gemm_f16_dec math) -> recon -> out
// Numerics: z, codes bit-identical to r21 (same split/MFMA orders); recon
// bit-identical (same K-order, same fp32->f16 q rounding); loss regrouped
// (512 partials vs 1024, last-bit change only).
// ---------------------------------------------------------------------------
__global__ __launch_bounds__(256)
void fused_zvqdec_kernel(const float* __restrict__ hg,
                         const f16* __restrict__ Bhg, const f16* __restrict__ Blg,
                         const float* __restrict__ be2,
                         const float* __restrict__ E0c, const float* __restrict__ E1c,
                         const float* __restrict__ E2c,
                         const f16* __restrict__ wp, const float* __restrict__ normg,
                         const float* __restrict__ bd1g, const float* __restrict__ bd2g,
                         float* __restrict__ out, float* __restrict__ partial){
  __shared__ __align__(16) char arena[137280];
  constexpr int VS = 132;   // rs stride (floats)
  constexpr int ES = 136;   // E/W/h2 stride (halves)

  const int tid  = threadIdx.x;
  const int wave = tid >> 6, lane = tid & 63;
  const int wm = wave >> 1, wn = wave & 1;
  const int lr = lane & 15, lg = lane >> 4;
  const long row0 = (long)blockIdx.x * 128;

  float* rs = (float*)arena;                       // [128*132] f32 (67584 B)
  f16*  Eh  = (f16*)(arena + 67584);               // [64*136]   (17408 B)
  f16*  El  = (f16*)(arena + 84992);               // [64*136]
  float* pE = (float*)(arena + 102400);            // [64]
  int*  besti = (int*)(arena + 102656);            // [3*128]
  float* wsum = (float*)(arena + 104192);          // [4]
  f16*  W1  = (f16*)(arena + 67584);               // dec: aliases Eh/El
  f16*  W2  = (f16*)(arena + 102400);              // dec: aliases pE/besti/wsum
  f16*  h2p = (f16*)arena;                         // dec: aliases rs (34816 B)

  // ================= Phase 1: GEMM2 z = h @ We2^T + be2 ====================
  {
    constexpr int RS = 40;
    f16* base = (f16*)arena;
    f16* AhL = base;           // [2][128*40] halves
    f16* AlL = base + 10240;
    f16* BhL = base + 20480;
    f16* BlL = base + 30720;
    const int K = D_IN;
    const int srow = tid >> 3, sc4 = tid & 7;     // A staging
    const int prow = tid >> 1, pkc = (tid & 1)*2; // B staging

    float4 pa[4];
    f16x8 pbh[2], pbl[2];
#pragma unroll
    for (int p = 0; p < 4; p++)
      pa[p] = *(const float4*)(hg + (row0 + p*32 + srow)*K + sc4*4);
#pragma unroll
    for (int c = 0; c < 2; c++){
      pbh[c] = *(const f16x8*)(Bhg + (long)prow*K + (pkc+c)*8);
      pbl[c] = *(const f16x8*)(Blg + (long)prow*K + (pkc+c)*8);
    }
#pragma unroll
    for (int p = 0; p < 4; p++){
      f16x4 h4, l4; split4(pa[p], h4, l4);
      *(f16x4*)&AhL[(p*32 + srow)*RS + sc4*4] = h4;
      *(f16x4*)&AlL[(p*32 + srow)*RS + sc4*4] = l4;
    }
#pragma unroll
    for (int c = 0; c < 2; c++){
      *(f16x8*)&BhL[prow*RS + (pkc+c)*8] = pbh[c];
      *(f16x8*)&BlL[prow*RS + (pkc+c)*8] = pbl[c];
    }
    __syncthreads();

    f32x4 accm[4][4], accc[4][4];
#pragma unroll
    for (int i = 0; i < 4; i++)
#pragma unroll
      for (int j = 0; j < 4; j++){
        accm[i][j] = (f32x4){0.f,0.f,0.f,0.f};
        accc[i][j] = (f32x4){0.f,0.f,0.f,0.f};
      }

    const int nt = K >> 5;
    int cur = 0;
    for (int t = 0; t < nt; t++){
      const bool more = (t + 1 < nt);
      if (more){
        const long ko = (long)(t+1)*32;
#pragma unroll
        for (int p = 0; p < 4; p++)
          pa[p] = *(const float4*)(hg + (row0 + p*32 + srow)*K + ko + sc4*4);
#pragma unroll
        for (int c = 0; c < 2; c++){
          pbh[c] = *(const f16x8*)(Bhg + (long)prow*K + ko + (pkc+c)*8);
          pbl[c] = *(const f16x8*)(Blg + (long)prow*K + ko + (pkc+c)*8);
        }
      }
      f16x8 ah[4], al[4];
#pragma unroll
      for (int mi = 0; mi < 4; mi++){
        int row = wm*64 + mi*16 + lr;
        ah[mi] = *(const f16x8*)&AhL[cur*5120 + row*RS + lg*8];
        al[mi] = *(const f16x8*)&AlL[cur*5120 + row*RS + lg*8];
      }
#pragma unroll
      for (int ni = 0; ni < 4; ni++){
        int col = wn*64 + ni*16 + lr;
        f16x8 bh = *(const f16x8*)&BhL[cur*5120 + col*RS + lg*8];
        f16x8 bl = *(const f16x8*)&BlL[cur*5120 + col*RS + lg*8];
#pragma unroll
        for (int mi = 0; mi < 4; mi++){
          accm[mi][ni] = __builtin_amdgcn_mfma_f32_16x16x32_f16(ah[mi], bh, accm[mi][ni], 0, 0, 0);
          accc[mi][ni] = __builtin_amdgcn_mfma_f32_16x16x32_f16(ah[mi], bl, accc[mi][ni], 0, 0, 0);
          accc[mi][ni] = __builtin_amdgcn_mfma_f32_16x16x32_f16(al[mi], bh, accc[mi][ni], 0, 0, 0);
        }
      }
      if (more){
        int nb = cur ^ 1;
#pragma unroll
        for (int p = 0; p < 4; p++){
          f16x4 h4, l4; split4(pa[p], h4, l4);
          *(f16x4*)&AhL[nb*5120 + (p*32 + srow)*RS + sc4*4] = h4;
          *(f16x4*)&AlL[nb*5120 + (p*32 + srow)*RS + sc4*4] = l4;
        }
#pragma unroll
        for (int c = 0; c < 2; c++){
          *(f16x8*)&BhL[nb*5120 + prow*RS + (pkc+c)*8] = pbh[c];
          *(f16x8*)&BlL[nb*5120 + prow*RS + (pkc+c)*8] = pbl[c];
        }
        __syncthreads();
        cur = nb;
      }
    }

    __syncthreads();   // all MFMA reads of GEMM buffers done before rs overwrite
    float bv[4];
#pragma unroll
    for (int ni = 0; ni < 4; ni++) bv[ni] = be2[wn*64 + ni*16 + lr];
#pragma unroll
    for (int mi = 0; mi < 4; mi++)
#pragma unroll
      for (int ni = 0; ni < 4; ni++)
#pragma unroll
        for (int r = 0; r < 4; r++){
          float v = accm[mi][ni][r] + accc[mi][ni][r]*(1.0f/2048.0f) + bv[ni];
          rs[(wm*64 + mi*16 + lg*4 + r)*VS + wn*64 + ni*16 + lr] = v;
        }
  }

  // ================= Phase 2: residual VQ on rs (128 rows) =================
  float4 qa[16];
#pragma unroll
  for (int j = 0; j < 16; j++) qa[j] = make_float4(0.f,0.f,0.f,0.f);
  float lsum = 0.f;

  const int urow = tid & 127, uh = tid >> 7;   // update coords (2 thr/row)
  const int sc = tid & 63, sq = tid >> 6;      // E staging coords

  const float* Etab[3] = {E0c, E1c, E2c};
  const int    Ktab[3] = {8, 64, 512};
  const long   EHt[3]  = {E0H, E1H, E2H};
  const long   ELt[3]  = {E0L, E1L, E2L};
  const int    NOt[3]  = {0, 8, 72};

  for (int l = 0; l < 3; l++){
    const float* E = Etab[l];
    const int K = Ktab[l];
    const f16* Ehg = wp + EHt[l];
    const f16* Elg = wp + ELt[l];
    const float* nrm = normg + NOt[l];

    __syncthreads();   // rs (z or updated residual) visible
    f16x8 ah[2][4], al[2][4];
#pragma unroll
    for (int rg = 0; rg < 2; rg++)
#pragma unroll
      for (int ks = 0; ks < 4; ks++){
        float av[8];
        *(float4*)&av[0] = *(const float4*)&rs[(wave*32 + rg*16 + lr)*VS + ks*32 + lg*8];
        *(float4*)&av[4] = *(const float4*)&rs[(wave*32 + rg*16 + lr)*VS + ks*32 + lg*8 + 4];
        split8_reg(av, ah[rg][ks], al[rg][ks]);
      }

    float bd[2][4]; int bi[2][4];
#pragma unroll
    for (int rg = 0; rg < 2; rg++)
#pragma unroll
      for (int r = 0; r < 4; r++){ bd[rg][r] = 3.0e38f; bi[rg][r] = 0x7fffffff; }

    for (int kbase = 0; kbase < K; kbase += 64){
      const int cn = (K - kbase < 64) ? (K - kbase) : 64;
      __syncthreads();
      if (sc < cn){
        long go = (long)(kbase + sc)*D_EMB + sq*32;
#pragma unroll
        for (int j = 0; j < 4; j++){
          *(f16x8*)&Eh[sc*ES + sq*32 + j*8] = *(const f16x8*)(Ehg + go + j*8);
          *(f16x8*)&El[sc*ES + sq*32 + j*8] = *(const f16x8*)(Elg + go + j*8);
        }
        if (sq == 0) pE[sc] = nrm[kbase + sc];
      } else {
        f16x8 zz;
#pragma unroll
        for (int i = 0; i < 8; i++) zz[i] = (_Float16)0.f;
#pragma unroll
        for (int j = 0; j < 4; j++){
          *(f16x8*)&Eh[sc*ES + sq*32 + j*8] = zz;
          *(f16x8*)&El[sc*ES + sq*32 + j*8] = zz;
        }
        if (sq == 0) pE[sc] = 3.0e38f;
      }
      __syncthreads();

      const int cgmax = (cn + 15) >> 4;
      for (int cg = 0; cg < cgmax; cg++){
        f32x4 Sm[2], Sc2[2];
#pragma unroll
        for (int rg = 0; rg < 2; rg++){
          Sm[rg]  = (f32x4){0.f,0.f,0.f,0.f};
          Sc2[rg] = (f32x4){0.f,0.f,0.f,0.f};
        }
#pragma unroll
        for (int ks = 0; ks < 4; ks++){
          f16x8 bh = *(const f16x8*)&Eh[(cg*16 + lr)*ES + ks*32 + lg*8];
          f16x8 bl = *(const f16x8*)&El[(cg*16 + lr)*ES + ks*32 + lg*8];
#pragma unroll
          for (int rg = 0; rg < 2; rg++){
            Sm[rg]  = __builtin_amdgcn_mfma_f32_16x16x32_f16(ah[rg][ks], bh, Sm[rg], 0, 0, 0);
            Sc2[rg] = __builtin_amdgcn_mfma_f32_16x16x32_f16(ah[rg][ks], bl, Sc2[rg], 0, 0, 0);
            Sc2[rg] = __builtin_amdgcn_mfma_f32_16x16x32_f16(al[rg][ks], bh, Sc2[rg], 0, 0, 0);
          }
        }
        int code = cg*16 + lr;
        float ne = pE[code];
        int kg = kbase + code;
#pragma unroll
        for (int rg = 0; rg < 2; rg++)
#pragma unroll
          for (int r = 0; r < 4; r++){
            float S  = fmaf(Sc2[rg][r], 1.0f/2048.0f, Sm[rg][r]);
            float sd = fmaf(-2.0f, S, ne);
            if (sd < bd[rg][r]){ bd[rg][r] = sd; bi[rg][r] = kg; }
          }
      }
    }

#pragma unroll
    for (int rg = 0; rg < 2; rg++)
#pragma unroll
      for (int r = 0; r < 4; r++){
#pragma unroll
        for (int off = 1; off < 16; off <<= 1){
          float ob = __shfl_xor(bd[rg][r], off, 16);
          int   oi = __shfl_xor(bi[rg][r], off, 16);
          if (ob < bd[rg][r] || (ob == bd[rg][r] && oi < bi[rg][r])){ bd[rg][r] = ob; bi[rg][r] = oi; }
        }
        if (lr == 0) besti[l*128 + wave*32 + rg*16 + lg*4 + r] = bi[rg][r];
      }
    __syncthreads();

    {
      int k = besti[l*128 + urow];
      const float* Er = E + (long)k*D_EMB + uh*64;
#pragma unroll
      for (int j = 0; j < 16; j++){
        float4 e = *(const float4*)&Er[j*4];
        float* rp = &rs[urow*VS + uh*64 + j*4];
        float4 r = *(const float4*)rp;
        float4 df = make_float4(e.x-r.x, e.y-r.y, e.z-r.z, e.w-r.w);
        lsum += dot4(df, df);
        *(float4*)rp = make_float4(r.x-e.x, r.y-e.y, r.z-e.z, r.w-e.w);
        qa[j].x += e.x; qa[j].y += e.y; qa[j].z += e.z; qa[j].w += e.w;
      }
    }
  }

  // codes out (besti final)
  if (tid < 128){
    long n = row0 + tid;
    for (int l = 0; l < 3; l++)
      out[CODES_OFF + n*3 + l] = (float)besti[l*128 + tid];
  }
  // loss partial (before wsum region is aliased by W2)
  for (int off = 32; off > 0; off >>= 1) lsum += __shfl_down(lsum, off);
  if ((tid & 63) == 0) wsum[wave] = lsum;
  __syncthreads();
  if (tid == 0) partial[blockIdx.x] = wsum[0] + wsum[1] + wsum[2] + wsum[3];
  // q -> rs (each thread overwrites its own residual slots)
#pragma unroll
  for (int j = 0; j < 16; j++)
    *(float4*)&rs[urow*VS + uh*64 + j*4] = qa[j];
  __syncthreads();   // wsum consumed, q visible

  // ================= Phase 3: decoder (dec1 + dec2) ========================
  {
    const int srow = tid >> 1, sco = (tid & 1)*64;
    // stage Wd1 -> W1, Wd2 -> W2 (aliases dead Eh/El/pE/besti/wsum)
#pragma unroll
    for (int c = 0; c < 8; c++){
      *(f16x8*)&W1[srow*ES + sco + c*8] = *(const f16x8*)(wp + WD1F + (long)srow*128 + sco + c*8);
      *(f16x8*)&W2[srow*ES + sco + c*8] = *(const f16x8*)(wp + WD2F + (long)srow*128 + sco + c*8);
    }
    // load q A-frags (fp32 -> f16 cast, same rounding as r21 q16 path)
    f16x8 a1[2][4];
#pragma unroll
    for (int rg = 0; rg < 2; rg++)
#pragma unroll
      for (int ks = 0; ks < 4; ks++){
        float av[8];
        *(float4*)&av[0] = *(const float4*)&rs[(wave*32 + rg*16 + lr)*VS + ks*32 + lg*8];
        *(float4*)&av[4] = *(const float4*)&rs[(wave*32 + rg*16 + lr)*VS + ks*32 + lg*8 + 4];
#pragma unroll
        for (int i = 0; i < 8; i++) a1[rg][ks][i] = (_Float16)av[i];
      }
    __syncthreads();   // W staged; all q reads done (h2 may overwrite rs)

    // dec1: h2 = relu(q @ Wd1^T + bd1)
    f32x4 acc[2][8];
#pragma unroll
    for (int rg = 0; rg < 2; rg++)
#pragma unroll
      for (int nf = 0; nf < 8; nf++) acc[rg][nf] = (f32x4){0.f,0.f,0.f,0.f};
#pragma unroll
    for (int ks = 0; ks < 4; ks++)
#pragma unroll
      for (int nf = 0; nf < 8; nf++){
        f16x8 b = *(const f16x8*)&W1[(nf*16 + lr)*ES + ks*32 + lg*8];
#pragma unroll
        for (int rg = 0; rg < 2; rg++)
          acc[rg][nf] = __builtin_amdgcn_mfma_f32_16x16x32_f16(a1[rg][ks], b, acc[rg][nf], 0, 0, 0);
      }
    float bv1[8];
#pragma unroll
    for (int nf = 0; nf < 8; nf++) bv1[nf] = bd1g[nf*16 + lr];
#pragma unroll
    for (int rg = 0; rg < 2; rg++)
#pragma unroll
      for (int nf = 0; nf < 8; nf++)
#pragma unroll
        for (int r = 0; r < 4; r++){
          float v = fmaxf(acc[rg][nf][r] + bv1[nf], 0.f);
          h2p[(wave*32 + rg*16 + lg*4 + r)*ES + nf*16 + lr] = (_Float16)v;
        }
    __syncthreads();   // h2 visible

    // dec2: recon = h2 @ Wd2^T + bd2 -> global
    f16x8 a2[2][4];
#pragma unroll
    for (int rg = 0; rg < 2; rg++)
#pragma unroll
      for (int ks = 0; ks < 4; ks++)
        a2[rg][ks] = *(const f16x8*)&h2p[(wave*32 + rg*16 + lr)*ES + ks*32 + lg*8];
#pragma unroll
    for (int rg = 0; rg < 2; rg++)
#pragma unroll
      for (int nf = 0; nf < 8; nf++) acc[rg][nf] = (f32x4){0.f,0.f,0.f,0.f};
#pragma unroll
    for (int ks = 0; ks < 4; ks++)
#pragma unroll
      for (int nf = 0; nf < 8; nf++){
        f16x8 b = *(const f16x8*)&W2[(nf*16 + lr)*ES + ks*32 + lg*8];
#pragma unroll
        for (int rg = 0; rg < 2; rg++)
          acc[rg][nf] = __builtin_amdgcn_mfma_f32_16x16x32_f16(a2[rg][ks], b, acc[rg][nf], 0, 0, 0);
      }
    float bv2[8];
#pragma unroll
    for (int nf = 0; nf < 8; nf++) bv2[nf] = bd2g[nf*16 + lr];
#pragma unroll
    for (int rg = 0; rg < 2; rg++)
#pragma unroll
      for (int nf = 0; nf < 8; nf++)
#pragma unroll
        for (int r = 0; r < 4; r++){
          long row = row0 + wave*32 + rg*16 + lg*4 + r;
          out[row*D_EMB + nf*16 + lr] = acc[rg][nf][r] + bv2[nf];
        }
  }
}

__global__ __launch_bounds__(256)
void loss_reduce_kernel(const float* __restrict__ partial, float* __restrict__ out){
  __shared__ float ws2[4];
  int tid = threadIdx.x;
  float s = 0.f;
  for (int i = tid; i < 512; i += 256) s += partial[i];
  for (int off = 32; off > 0; off >>= 1) s += __shfl_down(s, off);
  if ((tid & 63) == 0) ws2[tid >> 6] = s;
  __syncthreads();
  if (tid == 0)
    out[LOSS_OFF] = (ws2[0] + ws2[1] + ws2[2] + ws2[3]) * (0.25f / (float)((long)NROWS * D_EMB));
}

extern "C" void kernel_launch(void* const* d_in, const int* in_sizes, int n_in,
                              void* d_out, int out_size, void* d_ws, size_t ws_size,
                              hipStream_t stream) {
  (void)in_sizes; (void)n_in; (void)out_size; (void)ws_size;
  const float* x   = (const float*)d_in[0];
  const float* We1 = (const float*)d_in[1];
  const float* be1 = (const float*)d_in[2];
  const float* We2 = (const float*)d_in[3];
  const float* be2 = (const float*)d_in[4];
  const float* Wd1 = (const float*)d_in[5];
  const float* bd1 = (const float*)d_in[6];
  const float* Wd2 = (const float*)d_in[7];
  const float* bd2 = (const float*)d_in[8];
  const float* E0  = (const float*)d_in[9];
  const float* E1  = (const float*)d_in[10];
  const float* E2  = (const float*)d_in[11];
  float* out = (float*)d_out;
  char*  ws  = (char*)d_ws;

  // Layout: h at ws[0,192MiB); plane arena at ws+192MiB; partial/norms beyond.
  float* h    = (float*)ws;
  f16*   wp   = (f16*)(ws + WOFF);
  float* partial = (float*)(ws + PARTIAL_B);
  float* norms   = (float*)(ws + NORM_B);

  dim3 blk(256);
  split_weights_kernel<<<dim3(777), blk, 0, stream>>>(We1, We2, Wd1, Wd2, E0, E1, E2, wp);
  enorm_kernel<<<dim3(3), blk, 0, stream>>>(E0, E1, E2, norms);
  gemm_v2_kernel<true><<<dim3(D_IN/128, NROWS/256), dim3(512), 0, stream>>>(
      x, wp+WE1H, wp+WE1L, be1, h, NROWS, D_IN, D_IN);
  fused_zvqdec_kernel<<<dim3(NROWS/128), blk, 0, stream>>>(
      h, wp+WE2H, wp+WE2L, be2, E0, E1, E2, wp, norms, bd1, bd2, out, partial);
  loss_reduce_kernel<<<dim3(1), blk, 0, stream>>>(partial, out);
}

// Round 23
// 453.033 us; speedup vs baseline: 1.0478x; 1.0478x over previous
//
#include <hip/hip_runtime.h>

typedef _Float16 f16;
typedef __attribute__((ext_vector_type(4))) _Float16 f16x4;
typedef __attribute__((ext_vector_type(8))) _Float16 f16x8;
typedef __attribute__((ext_vector_type(4))) float    f32x4;

static constexpr int NROWS = 65536;
static constexpr int D_IN  = 768;
static constexpr int D_EMB = 128;
static constexpr long LOSS_OFF  = (long)NROWS * D_EMB;   // 8388608
static constexpr long CODES_OFF = LOSS_OFF + 1;

// weight/codebook plane arena at ws+WOFF (offsets in halves)
static constexpr long WOFF = 201326592L;
static constexpr long WE1H = 0,       WE1L = 589824;
static constexpr long WE2H = 1179648, WE2L = 1277952;
static constexpr long WD1F = 1376256, WD2F = 1392640;   // decoder f16 cast
static constexpr long E0H = 1409024, E0L = 1410048;     // codebook planes
static constexpr long E1H = 1411072, E1L = 1419264;
static constexpr long E2H = 1427456, E2L = 1492992;     // ends 1558528 halves
static constexpr long PARTIAL_B = WOFF + 4194304L;      // 1024 f32
static constexpr long NORM_B    = WOFF + 4198400L;      // 584 f32

__device__ __forceinline__ float dot4(float4 a, float4 b){
  return fmaf(a.x,b.x, fmaf(a.y,b.y, fmaf(a.z,b.z, a.w*b.w)));
}

// fp32 -> f16 hi + f16 lo*2^-11 (lo pre-scaled by 2048, stays normal-range)
__device__ __forceinline__ void split4(float4 v, f16x4& hi, f16x4& lo){
  _Float16 h0=(_Float16)v.x, h1=(_Float16)v.y, h2=(_Float16)v.z, h3=(_Float16)v.w;
  hi[0]=h0; hi[1]=h1; hi[2]=h2; hi[3]=h3;
  lo[0]=(_Float16)((v.x-(float)h0)*2048.0f);
  lo[1]=(_Float16)((v.y-(float)h1)*2048.0f);
  lo[2]=(_Float16)((v.z-(float)h2)*2048.0f);
  lo[3]=(_Float16)((v.w-(float)h3)*2048.0f);
}

__device__ __forceinline__ void split8_reg(const float* v, f16x8& hi, f16x8& lo){
#pragma unroll
  for (int i = 0; i < 8; i++){
    _Float16 h = (_Float16)v[i];
    hi[i] = h;
    lo[i] = (_Float16)((v[i]-(float)h)*2048.0f);
  }
}

// ---------------------------------------------------------------------------
// One-shot prep (validated r16): weights+codebooks -> planes.
// ---------------------------------------------------------------------------
__global__ __launch_bounds__(256)
void split_weights_kernel(const float* __restrict__ We1, const float* __restrict__ We2,
                          const float* __restrict__ Wd1, const float* __restrict__ Wd2,
                          const float* __restrict__ E0,  const float* __restrict__ E1,
                          const float* __restrict__ E2,  f16* __restrict__ wp){
  int t = blockIdx.x*256 + threadIdx.x;
  if (t >= 198912) return;
  const float* src; long o4; long hO, lO; bool dual = true;
  if      (t < 147456){ src=We1; o4=t;        hO=WE1H; lO=WE1L; }
  else if (t < 172032){ src=We2; o4=t-147456; hO=WE2H; lO=WE2L; }
  else if (t < 176128){ src=Wd1; o4=t-172032; hO=WD1F; lO=0; dual=false; }
  else if (t < 180224){ src=Wd2; o4=t-176128; hO=WD2F; lO=0; dual=false; }
  else if (t < 180480){ src=E0;  o4=t-180224; hO=E0H;  lO=E0L; }
  else if (t < 182528){ src=E1;  o4=t-180480; hO=E1H;  lO=E1L; }
  else                { src=E2;  o4=t-182528; hO=E2H;  lO=E2L; }
  float4 v = *(const float4*)(src + o4*4);
  if (dual){
    f16x4 h4, l4; split4(v, h4, l4);
    *(f16x4*)(wp + hO + o4*4) = h4;
    *(f16x4*)(wp + lO + o4*4) = l4;
  } else {
    f16x4 h4; h4[0]=(_Float16)v.x; h4[1]=(_Float16)v.y; h4[2]=(_Float16)v.z; h4[3]=(_Float16)v.w;
    *(f16x4*)(wp + hO + o4*4) = h4;
  }
}

// Codebook norms, exact quarter-dot summation order (validated r16).
__global__ __launch_bounds__(256)
void enorm_kernel(const float* __restrict__ E0, const float* __restrict__ E1,
                  const float* __restrict__ E2, float* __restrict__ norms){
  int t = blockIdx.x*256 + threadIdx.x;
  if (t >= 584) return;
  const float* row;
  if (t < 8)       row = E0 + (long)t*128;
  else if (t < 72) row = E1 + (long)(t-8)*128;
  else             row = E2 + (long)(t-72)*128;
  float q[4];
#pragma unroll
  for (int sq = 0; sq < 4; sq++){
    float s = 0.f;
#pragma unroll
    for (int j = 0; j < 8; j++){
      float4 v = *(const float4*)(row + sq*32 + j*4);
      s += dot4(v, v);
    }
    q[sq] = s;
  }
  norms[t] = ((q[0] + q[1]) + q[2]) + q[3];
}

// ---------------------------------------------------------------------------
// Encoder GEMM (r17/r21 validated best): BM=256, BN=128, BK=32, 512 threads
// (8 waves, 4m x 2n), double-buffered LDS, ONE barrier per K-step, next
// tile's loads issued before the MFMA cluster, bijective XCD swizzle.
// ---------------------------------------------------------------------------
template<bool RELU>
__global__ __launch_bounds__(512, 2)
void gemm_v2_kernel(const float* __restrict__ A,
                    const f16* __restrict__ Bhg, const f16* __restrict__ Blg,
                    const float* __restrict__ bias, float* __restrict__ C,
                    int M, int N, int K){
  constexpr int RS = 40;
  __shared__ f16 AhL[2][256*RS];
  __shared__ f16 AlL[2][256*RS];
  __shared__ f16 BhL[2][128*RS];
  __shared__ f16 BlL[2][128*RS];

  const int tid = threadIdx.x;
  const int wave = tid >> 6, lane = tid & 63;
  const int wm = wave >> 1, wn = wave & 1;
  const int lr = lane & 15, lg = lane >> 4;

  // bijective XCD swizzle (panel-per-XCD; grids 1536/256 both % 8 == 0)
  const int gx  = gridDim.x;
  const int lid = blockIdx.y * gx + blockIdx.x;
  const int xcd = lid & 7;
  const int rr  = lid >> 3;
  const int bx  = rr % gx;
  const int by  = (rr / gx) * 8 + xcd;

  const long m0 = (long)by * 256;
  const long n0 = (long)bx * 128;

  const int ar = tid >> 3;
  const int ac = tid & 7;
  const int br = tid >> 2;
  const int bkc = tid & 3;

  const int nt = K >> 5;

  float4 pa[4];
  f16x8 pbh, pbl;

#pragma unroll
  for (int i = 0; i < 4; i++)
    pa[i] = *(const float4*)(A + (m0 + i*64 + ar)*K + ac*4);
  pbh = *(const f16x8*)(Bhg + (n0 + br)*K + bkc*8);
  pbl = *(const f16x8*)(Blg + (n0 + br)*K + bkc*8);

#pragma unroll
  for (int i = 0; i < 4; i++){
    f16x4 h4, l4; split4(pa[i], h4, l4);
    *(f16x4*)&AhL[0][(i*64 + ar)*RS + ac*4] = h4;
    *(f16x4*)&AlL[0][(i*64 + ar)*RS + ac*4] = l4;
  }
  *(f16x8*)&BhL[0][br*RS + bkc*8] = pbh;
  *(f16x8*)&BlL[0][br*RS + bkc*8] = pbl;
  __syncthreads();

  f32x4 accm[4][4], accc[4][4];
#pragma unroll
  for (int i = 0; i < 4; i++)
#pragma unroll
    for (int j = 0; j < 4; j++){
      accm[i][j] = (f32x4){0.f,0.f,0.f,0.f};
      accc[i][j] = (f32x4){0.f,0.f,0.f,0.f};
    }

  int cur = 0;
  for (int t = 0; t < nt; t++){
    const bool more = (t + 1 < nt);
    if (more){
      const long ko = (long)(t+1) * 32;
#pragma unroll
      for (int i = 0; i < 4; i++)
        pa[i] = *(const float4*)(A + (m0 + i*64 + ar)*K + ko + ac*4);
      pbh = *(const f16x8*)(Bhg + (n0 + br)*K + ko + bkc*8);
      pbl = *(const f16x8*)(Blg + (n0 + br)*K + ko + bkc*8);
    }

    f16x8 ah[4], al[4];
#pragma unroll
    for (int mi = 0; mi < 4; mi++){
      int row = wm*64 + mi*16 + lr;
      ah[mi] = *(const f16x8*)&AhL[cur][row*RS + lg*8];
      al[mi] = *(const f16x8*)&AlL[cur][row*RS + lg*8];
    }
#pragma unroll
    for (int ni = 0; ni < 4; ni++){
      int col = wn*64 + ni*16 + lr;
      f16x8 bh = *(const f16x8*)&BhL[cur][col*RS + lg*8];
      f16x8 bl = *(const f16x8*)&BlL[cur][col*RS + lg*8];
#pragma unroll
      for (int mi = 0; mi < 4; mi++){
        accm[mi][ni] = __builtin_amdgcn_mfma_f32_16x16x32_f16(ah[mi], bh, accm[mi][ni], 0, 0, 0);
        accc[mi][ni] = __builtin_amdgcn_mfma_f32_16x16x32_f16(ah[mi], bl, accc[mi][ni], 0, 0, 0);
        accc[mi][ni] = __builtin_amdgcn_mfma_f32_16x16x32_f16(al[mi], bh, accc[mi][ni], 0, 0, 0);
      }
    }

    if (more){
      int nb = cur ^ 1;
#pragma unroll
      for (int i = 0; i < 4; i++){
        f16x4 h4, l4; split4(pa[i], h4, l4);
        *(f16x4*)&AhL[nb][(i*64 + ar)*RS + ac*4] = h4;
        *(f16x4*)&AlL[nb][(i*64 + ar)*RS + ac*4] = l4;
      }
      *(f16x8*)&BhL[nb][br*RS + bkc*8] = pbh;
      *(f16x8*)&BlL[nb][br*RS + bkc*8] = pbl;
      __syncthreads();
      cur = nb;
    }
  }

  float bv[4];
#pragma unroll
  for (int ni = 0; ni < 4; ni++) bv[ni] = bias[n0 + wn*64 + ni*16 + lr];
#pragma unroll
  for (int mi = 0; mi < 4; mi++){
#pragma unroll
    for (int ni = 0; ni < 4; ni++){
#pragma unroll
      for (int r = 0; r < 4; r++){
        float v = accm[mi][ni][r] + accc[mi][ni][r]*(1.0f/2048.0f) + bv[ni];
        if (RELU) v = fmaxf(v, 0.f);
        long row = m0 + wm*64 + mi*16 + lg*4 + r;
        C[row*N + n0 + wn*64 + ni*16 + lr] = v;
      }
    }
  }
}

// ---------------------------------------------------------------------------
// Decoder GEMM, pure fp16 single plane (validated round 8).
// ---------------------------------------------------------------------------
template<bool RELU, bool OUT16>
__global__ __launch_bounds__(256)
void gemm_f16_dec(const f16* __restrict__ Ag, const f16* __restrict__ Bg,
                  const float* __restrict__ bias,
                  float* __restrict__ C32, f16* __restrict__ C16, int M){
  constexpr int RS = 136;
  __shared__ f16 As[128*RS];
  __shared__ f16 Bs[128*RS];
  const int tid = threadIdx.x;
  const int wave = tid >> 6, lane = tid & 63;
  const int wm = wave >> 1, wn = wave & 1;
  const int lr = lane & 15, lg = lane >> 4;
  const long m0 = (long)blockIdx.y * 128;
  const int srow = tid >> 1, sco = (tid & 1) * 64;

#pragma unroll
  for (int c = 0; c < 8; c++){
    *(f16x8*)&As[srow*RS + sco + c*8] = *(const f16x8*)(Ag + (m0+srow)*128 + sco + c*8);
    *(f16x8*)&Bs[srow*RS + sco + c*8] = *(const f16x8*)(Bg + (long)srow*128 + sco + c*8);
  }
  __syncthreads();

  f32x4 acc[4][4];
#pragma unroll
  for (int i = 0; i < 4; i++)
#pragma unroll
    for (int j = 0; j < 4; j++) acc[i][j] = (f32x4){0.f,0.f,0.f,0.f};

#pragma unroll
  for (int ks = 0; ks < 4; ks++){
    f16x8 a[4];
#pragma unroll
    for (int mi = 0; mi < 4; mi++)
      a[mi] = *(const f16x8*)&As[(wm*64 + mi*16 + lr)*RS + ks*32 + lg*8];
#pragma unroll
    for (int ni = 0; ni < 4; ni++){
      f16x8 b = *(const f16x8*)&Bs[(wn*64 + ni*16 + lr)*RS + ks*32 + lg*8];
#pragma unroll
      for (int mi = 0; mi < 4; mi++)
        acc[mi][ni] = __builtin_amdgcn_mfma_f32_16x16x32_f16(a[mi], b, acc[mi][ni], 0, 0, 0);
    }
  }

  float bv[4];
#pragma unroll
  for (int ni = 0; ni < 4; ni++) bv[ni] = bias[wn*64 + ni*16 + lr];
#pragma unroll
  for (int mi = 0; mi < 4; mi++){
#pragma unroll
    for (int ni = 0; ni < 4; ni++){
#pragma unroll
      for (int r = 0; r < 4; r++){
        float v = acc[mi][ni][r] + bv[ni];
        if (RELU) v = fmaxf(v, 0.f);
        long row = m0 + wm*64 + mi*16 + lg*4 + r;
        long col = wn*64 + ni*16 + lr;
        if (OUT16) C16[row*128 + col] = (_Float16)v;
        else       C32[row*128 + col] = v;
      }
    }
  }
}

// ---------------------------------------------------------------------------
// Fused residual-VQ with MFMA distances; pre-split codebook planes + norms
// (validated round 16).
// ---------------------------------------------------------------------------
__global__ __launch_bounds__(256)
void vq_mfma_kernel(const float* __restrict__ z,
                    const float* __restrict__ E0c, const float* __restrict__ E1c,
                    const float* __restrict__ E2c,
                    const f16* __restrict__ wp, const float* __restrict__ normg,
                    f16* __restrict__ q16, float* __restrict__ out,
                    float* __restrict__ partial){
  constexpr int VS = 132;
  constexpr int ES = 136;
  __shared__ float rs[64*VS];
  __shared__ f16 Eh[64*ES];
  __shared__ f16 El[64*ES];
  __shared__ float pE[64];
  __shared__ int   besti[3*64];
  __shared__ float wsum[4];

  const int tid  = threadIdx.x;
  const int wave = tid >> 6, lane = tid & 63;
  const int lr = lane & 15, lg = lane >> 4;
  const int row0 = blockIdx.x * 64;
  const int urow = tid & 63, uq = tid >> 6;
  const int sc = tid & 63, sq = tid >> 6;

#pragma unroll
  for (int i = 0; i < 8; i++){
    int idx = i*256 + tid;
    int r = idx >> 5, c = (idx & 31) * 4;
    *(float4*)&rs[r*VS + c] = *(const float4*)&z[(long)(row0 + r)*D_EMB + c];
  }

  float4 qa[8];
#pragma unroll
  for (int j = 0; j < 8; j++) qa[j] = make_float4(0.f,0.f,0.f,0.f);
  float lsum = 0.f;

  const float* Etab[3] = {E0c, E1c, E2c};
  const int    Ktab[3] = {8, 64, 512};
  const long   EHt[3]  = {E0H, E1H, E2H};
  const long   ELt[3]  = {E0L, E1L, E2L};
  const int    NOt[3]  = {0, 8, 72};

  for (int l = 0; l < 3; l++){
    const float* E = Etab[l];
    const int K = Ktab[l];
    const f16* Ehg = wp + EHt[l];
    const f16* Elg = wp + ELt[l];
    const float* nrm = normg + NOt[l];

    __syncthreads();
    f16x8 ah[4], al[4];
#pragma unroll
    for (int ks = 0; ks < 4; ks++){
      float av[8];
      *(float4*)&av[0] = *(const float4*)&rs[(wave*16 + lr)*VS + ks*32 + lg*8];
      *(float4*)&av[4] = *(const float4*)&rs[(wave*16 + lr)*VS + ks*32 + lg*8 + 4];
      split8_reg(av, ah[ks], al[ks]);
    }

    float bd[4]; int bi[4];
#pragma unroll
    for (int r = 0; r < 4; r++){ bd[r] = 3.0e38f; bi[r] = 0x7fffffff; }

    for (int kbase = 0; kbase < K; kbase += 64){
      const int cn = (K - kbase < 64) ? (K - kbase) : 64;
      __syncthreads();
      if (sc < cn){
        long go = (long)(kbase + sc)*D_EMB + sq*32;
#pragma unroll
        for (int j = 0; j < 4; j++){
          *(f16x8*)&Eh[sc*ES + sq*32 + j*8] = *(const f16x8*)(Ehg + go + j*8);
          *(f16x8*)&El[sc*ES + sq*32 + j*8] = *(const f16x8*)(Elg + go + j*8);
        }
        if (sq == 0) pE[sc] = nrm[kbase + sc];
      } else {
        f16x8 zz;
#pragma unroll
        for (int i = 0; i < 8; i++) zz[i] = (_Float16)0.f;
#pragma unroll
        for (int j = 0; j < 4; j++){
          *(f16x8*)&Eh[sc*ES + sq*32 + j*8] = zz;
          *(f16x8*)&El[sc*ES + sq*32 + j*8] = zz;
        }
        if (sq == 0) pE[sc] = 3.0e38f;
      }
      __syncthreads();

      const int cgmax = (cn + 15) >> 4;
      for (int cg = 0; cg < cgmax; cg++){
        f32x4 Sm = (f32x4){0.f,0.f,0.f,0.f};
        f32x4 Sc = (f32x4){0.f,0.f,0.f,0.f};
#pragma unroll
        for (int ks = 0; ks < 4; ks++){
          f16x8 bh = *(const f16x8*)&Eh[(cg*16 + lr)*ES + ks*32 + lg*8];
          f16x8 bl = *(const f16x8*)&El[(cg*16 + lr)*ES + ks*32 + lg*8];
          Sm = __builtin_amdgcn_mfma_f32_16x16x32_f16(ah[ks], bh, Sm, 0, 0, 0);
          Sc = __builtin_amdgcn_mfma_f32_16x16x32_f16(ah[ks], bl, Sc, 0, 0, 0);
          Sc = __builtin_amdgcn_mfma_f32_16x16x32_f16(al[ks], bh, Sc, 0, 0, 0);
        }
        int code = cg*16 + lr;
        float ne = pE[code];
        int kg = kbase + code;
#pragma unroll
        for (int r = 0; r < 4; r++){
          float S  = fmaf(Sc[r], 1.0f/2048.0f, Sm[r]);
          float sd = fmaf(-2.0f, S, ne);
          if (sd < bd[r]){ bd[r] = sd; bi[r] = kg; }
        }
      }
    }

#pragma unroll
    for (int r = 0; r < 4; r++){
#pragma unroll
      for (int off = 1; off < 16; off <<= 1){
        float ob = __shfl_xor(bd[r], off, 16);
        int   oi = __shfl_xor(bi[r], off, 16);
        if (ob < bd[r] || (ob == bd[r] && oi < bi[r])){ bd[r] = ob; bi[r] = oi; }
      }
      if (lr == 0) besti[l*64 + wave*16 + lg*4 + r] = bi[r];
    }
    __syncthreads();

    {
      int k = besti[l*64 + urow];
      const float* Er = E + (long)k*D_EMB + uq*32;
#pragma unroll
      for (int j = 0; j < 8; j++){
        float4 e = *(const float4*)&Er[j*4];
        float* rp = &rs[urow*VS + uq*32 + j*4];
        float4 r = *(const float4*)rp;
        float4 df = make_float4(e.x-r.x, e.y-r.y, e.z-r.z, e.w-r.w);
        lsum += dot4(df, df);
        *(float4*)rp = make_float4(r.x-e.x, r.y-e.y, r.z-e.z, r.w-e.w);
        qa[j].x += e.x; qa[j].y += e.y; qa[j].z += e.z; qa[j].w += e.w;
      }
    }
  }

  __syncthreads();
#pragma unroll
  for (int j = 0; j < 8; j++)
    *(float4*)&rs[urow*VS + uq*32 + j*4] = qa[j];
  __syncthreads();
#pragma unroll
  for (int i = 0; i < 8; i++){
    int idx = i*256 + tid;
    int r = idx >> 5, c = (idx & 31) * 4;
    float4 v = *(const float4*)&rs[r*VS + c];
    f16x4 h4; h4[0]=(_Float16)v.x; h4[1]=(_Float16)v.y; h4[2]=(_Float16)v.z; h4[3]=(_Float16)v.w;
    *(f16x4*)&q16[(long)(row0 + r)*D_EMB + c] = h4;
  }
  if (tid < 64){
    long n = row0 + tid;
    for (int l = 0; l < 3; l++)
      out[CODES_OFF + n*3 + l] = (float)besti[l*64 + tid];
  }
  for (int off = 32; off > 0; off >>= 1) lsum += __shfl_down(lsum, off);
  if ((tid & 63) == 0) wsum[tid >> 6] = lsum;
  __syncthreads();
  if (tid == 0) partial[blockIdx.x] = wsum[0] + wsum[1] + wsum[2] + wsum[3];
}

__global__ __launch_bounds__(256)
void loss_reduce_kernel(const float* __restrict__ partial, float* __restrict__ out){
  __shared__ float ws2[4];
  int tid = threadIdx.x;
  float s = 0.f;
  for (int i = tid; i < 1024; i += 256) s += partial[i];
  for (int off = 32; off > 0; off >>= 1) s += __shfl_down(s, off);
  if ((tid & 63) == 0) ws2[tid >> 6] = s;
  __syncthreads();
  if (tid == 0)
    out[LOSS_OFF] = (ws2[0] + ws2[1] + ws2[2] + ws2[3]) * (0.25f / (float)((long)NROWS * D_EMB));
}

extern "C" void kernel_launch(void* const* d_in, const int* in_sizes, int n_in,
                              void* d_out, int out_size, void* d_ws, size_t ws_size,
                              hipStream_t stream) {
  (void)in_sizes; (void)n_in; (void)out_size; (void)ws_size;
  const float* x   = (const float*)d_in[0];
  const float* We1 = (const float*)d_in[1];
  const float* be1 = (const float*)d_in[2];
  const float* We2 = (const float*)d_in[3];
  const float* be2 = (const float*)d_in[4];
  const float* Wd1 = (const float*)d_in[5];
  const float* bd1 = (const float*)d_in[6];
  const float* Wd2 = (const float*)d_in[7];
  const float* bd2 = (const float*)d_in[8];
  const float* E0  = (const float*)d_in[9];
  const float* E1  = (const float*)d_in[10];
  const float* E2  = (const float*)d_in[11];
  float* out = (float*)d_out;
  char*  ws  = (char*)d_ws;

  // Layout (validated; max use < 224 MiB):
  //   h fp32      : ws[0, 192MiB)       live GEMM1 -> GEMM2
  //   q16         : ws[0, 16MiB)        dead-h reuse (VQ -> GEMM3)
  //   h2_16       : ws+32MiB, 16MiB     dead-h reuse (GEMM3 -> GEMM4)
  //   plane arena : ws+192MiB (weights + codebooks, ~3.1MiB)
  //   partial     : ws+192MiB+4MiB; norms at +4MiB+4KiB
  //   z aliases d_out[0:8388608] (recon region)
  float* h    = (float*)ws;
  f16*   q16  = (f16*)ws;
  f16*   h216 = (f16*)(ws + 33554432L);
  f16*   wp   = (f16*)(ws + WOFF);
  float* partial = (float*)(ws + PARTIAL_B);
  float* norms   = (float*)(ws + NORM_B);
  float* z = out;

  dim3 blk(256);
  split_weights_kernel<<<dim3(777), blk, 0, stream>>>(We1, We2, Wd1, Wd2, E0, E1, E2, wp);
  enorm_kernel<<<dim3(3), blk, 0, stream>>>(E0, E1, E2, norms);
  gemm_v2_kernel<true ><<<dim3(D_IN/128,  NROWS/256), dim3(512), 0, stream>>>(
      x, wp+WE1H, wp+WE1L, be1, h, NROWS, D_IN,  D_IN);
  gemm_v2_kernel<false><<<dim3(D_EMB/128, NROWS/256), dim3(512), 0, stream>>>(
      h, wp+WE2H, wp+WE2L, be2, z, NROWS, D_EMB, D_IN);
  vq_mfma_kernel<<<dim3(NROWS/64), blk, 0, stream>>>(z, E0, E1, E2, wp, norms, q16, out, partial);
  loss_reduce_kernel<<<dim3(1), blk, 0, stream>>>(partial, out);
  gemm_f16_dec<true, true ><<<dim3(1, NROWS/128), blk, 0, stream>>>(q16,  wp+WD1F, bd1, nullptr, h216, NROWS);
  gemm_f16_dec<false,false><<<dim3(1, NROWS/128), blk, 0, stream>>>(h216, wp+WD2F, bd2, out, nullptr, NROWS);
}